// Round 2
// baseline (311.579 us; speedup 1.0000x reference)
//
#include <hip/hip_runtime.h>
#include <math.h>

#define NN 2048
#define BB 16
#define T1D 12
#define T2D 64
#define JJ (BB*T1D)   // 192 packed columns (b*12+u)

// workspace layout in floats (total ~4.7 MB)
#define OFF_DIS 0
#define OFF_E   2048
#define OFF_XH  4352
#define OFF_P1  (OFF_XH + NN*JJ)
#define OFF_P2  (OFF_P1 + NN*JJ)

// ---------------- deg -> dis = rsqrt(rowsum(A)) ----------------
// one wave per row, 4 rows per block, grid 512
__global__ __launch_bounds__(256) void k_deg(const float* __restrict__ A,
                                             float* __restrict__ dis) {
    int wid = threadIdx.x >> 6, lane = threadIdx.x & 63;
    int r = blockIdx.x * 4 + wid;
    const float4* Ar = (const float4*)(A + (size_t)r * NN);
    float s = 0.f;
#pragma unroll
    for (int i = 0; i < 8; ++i) {
        float4 v = Ar[i * 64 + lane];
        s += v.x + v.y + v.z + v.w;
    }
#pragma unroll
    for (int off = 32; off > 0; off >>= 1) s += __shfl_down(s, off);
    if (lane == 0) dis[r] = (s > 0.f) ? rsqrtf(s) : 0.f;
}

// ---------------- E[b] 12x12 ----------------
// one block per batch
__global__ __launch_bounds__(256) void k_prepE(const float* __restrict__ X,
                                               const float* __restrict__ U1,
                                               const float* __restrict__ U2,
                                               const float* __restrict__ U3,
                                               const float* __restrict__ be,
                                               const float* __restrict__ Ve,
                                               float* __restrict__ E_ws) {
    int b = blockIdx.x, tid = threadIdx.x;
    __shared__ float red[24][256];
    __shared__ float es[T1D][T1D];

    float accr[T1D], accc[T1D];
#pragma unroll
    for (int t = 0; t < T1D; ++t) { accr[t] = 0.f; accc[t] = 0.f; }

    for (int n = tid; n < NN; n += 256) {
        const float* xp = X + ((size_t)b * NN + n) * T1D;
        float x[T1D];
        *(float4*)&x[0] = *(const float4*)&xp[0];
        *(float4*)&x[4] = *(const float4*)&xp[4];
        *(float4*)&x[8] = *(const float4*)&xp[8];
        float u1 = U1[n], u2 = U2[n];
#pragma unroll
        for (int t = 0; t < T1D; ++t) {
            accr[t] += x[t] * u1;
            accc[t] += x[t] * u2;
        }
    }
#pragma unroll
    for (int t = 0; t < T1D; ++t) {
        red[t][tid] = accr[t];
        red[12 + t][tid] = accc[t];
    }
    __syncthreads();
    for (int s = 128; s > 0; s >>= 1) {
        if (tid < s) {
#pragma unroll
            for (int a = 0; a < 24; ++a) red[a][tid] += red[a][tid + s];
        }
        __syncthreads();
    }

    float u3 = U3[0];
    // Esc[t][s] = r[t]*c[s] + be[t][s]; softmax over t (axis=1) per column s
    if (tid < T1D) {
        int s = tid;
        float cs = red[12 + s][0] * u3;
        float vals[T1D];
        float m = -1e30f;
#pragma unroll
        for (int t = 0; t < T1D; ++t) {
            vals[t] = red[t][0] * cs + be[t * T1D + s];
            m = fmaxf(m, vals[t]);
        }
        float sum = 0.f;
#pragma unroll
        for (int t = 0; t < T1D; ++t) { vals[t] = expf(vals[t] - m); sum += vals[t]; }
        float inv = 1.f / sum;
#pragma unroll
        for (int t = 0; t < T1D; ++t) es[t][s] = vals[t] * inv;
    }
    __syncthreads();
    // Emid[t][u] = sum_s Ve[t][s]*es[s][u]; softmax over t; write E
    if (tid < T1D) {
        int u = tid;
        float vals[T1D];
        float m = -1e30f;
#pragma unroll
        for (int t = 0; t < T1D; ++t) {
            float acc = 0.f;
#pragma unroll
            for (int s = 0; s < T1D; ++s) acc += Ve[t * T1D + s] * es[s][u];
            vals[t] = acc;
            m = fmaxf(m, acc);
        }
        float sum = 0.f;
#pragma unroll
        for (int t = 0; t < T1D; ++t) { vals[t] = expf(vals[t] - m); sum += vals[t]; }
        float inv = 1.f / sum;
#pragma unroll
        for (int t = 0; t < T1D; ++t) E_ws[b * 144 + t * T1D + u] = vals[t] * inv;
    }
}

// ---------------- X_hat packed as Xh[n][b*12+u] ----------------
__global__ __launch_bounds__(256) void k_xhat(const float* __restrict__ X,
                                              const float* __restrict__ E_ws,
                                              float* __restrict__ Xh) {
    int g = blockIdx.x * 256 + threadIdx.x;  // < NN*JJ
    int n = g / JJ;
    int j = g - n * JJ;
    int b = j / T1D;
    int u = j - b * T1D;
    const float* xp = X + ((size_t)b * NN + n) * T1D;
    const float* ep = E_ws + b * 144 + u;
    float acc = 0.f;
#pragma unroll
    for (int t = 0; t < T1D; ++t) acc += xp[t] * ep[t * T1D];
    Xh[g] = acc;
}

// ---------------- GEMM: P[c][j] += dis[c] * sum_r A[r][c] * dis[r] * Z[r][j] ----
// grid (64 c-blocks, 4 k-splits), 256 threads, per-thread 4c x 6j
__global__ __launch_bounds__(256) void k_gemm(const float* __restrict__ A,
                                              const float* __restrict__ dis,
                                              const float* __restrict__ Z,
                                              float* __restrict__ P) {
    __shared__ float As[16 * 32];
    __shared__ float Zs[16 * JJ];
    int tid = threadIdx.x;
    int tc = tid >> 5, tj = tid & 31;
    int c0 = blockIdx.x * 32;
    int rbase = blockIdx.y * 512;

    float acc[4][6];
#pragma unroll
    for (int i = 0; i < 4; ++i)
#pragma unroll
        for (int l = 0; l < 6; ++l) acc[i][l] = 0.f;

    for (int ch = 0; ch < 32; ++ch) {
        int rk = rbase + ch * 16;
        // stage A tile [16][32]
        int ia = tid * 2;
        *(float2*)&As[ia] =
            *(const float2*)&A[(size_t)(rk + (ia >> 5)) * NN + c0 + (ia & 31)];
        // stage Z tile [16][192], row-scaled by dis[r]
#pragma unroll
        for (int v = 0; v < 3; ++v) {
            int iz = tid * 12 + v * 4;
            int zr = iz / JJ;
            int zj = iz - zr * JJ;
            float4 z = *(const float4*)&Z[(size_t)(rk + zr) * JJ + zj];
            float dr = dis[rk + zr];
            z.x *= dr; z.y *= dr; z.z *= dr; z.w *= dr;
            *(float4*)&Zs[iz] = z;
        }
        __syncthreads();
#pragma unroll
        for (int kk = 0; kk < 16; ++kk) {
            float4 a4 = *(float4*)&As[kk * 32 + tc * 4];
            const float* zr = &Zs[kk * JJ + tj * 6];
            float2 zA = *(const float2*)&zr[0];
            float2 zB = *(const float2*)&zr[2];
            float2 zC = *(const float2*)&zr[4];
            float av[4] = {a4.x, a4.y, a4.z, a4.w};
            float zv[6] = {zA.x, zA.y, zB.x, zB.y, zC.x, zC.y};
#pragma unroll
            for (int i = 0; i < 4; ++i)
#pragma unroll
                for (int l = 0; l < 6; ++l) acc[i][l] += av[i] * zv[l];
        }
        __syncthreads();
    }
#pragma unroll
    for (int i = 0; i < 4; ++i) {
        float dc = dis[c0 + tc * 4 + i];
#pragma unroll
        for (int l = 0; l < 6; ++l)
            atomicAdd(&P[(size_t)(c0 + tc * 4 + i) * JJ + tj * 6 + l], acc[i][l] * dc);
    }
}

// ---------------- out = relu(Xh(W0-W2) - P1*W1 + 2*P2*W2 + bcheb) ----------------
__global__ __launch_bounds__(256) void k_out(const float* __restrict__ Xh,
                                             const float* __restrict__ P1,
                                             const float* __restrict__ P2,
                                             const float* __restrict__ Wcheb,
                                             const float* __restrict__ bcheb,
                                             float* __restrict__ out) {
    int g = blockIdx.x * 256 + threadIdx.x;  // < BB*NN*T2D
    int o = g & 63;
    int row = g >> 6;          // b*2048+n
    int b = row >> 11;
    int n = row & 2047;
    int base = n * JJ + b * T1D;
    const float* xh = Xh + base;
    const float* p1 = P1 + base;
    const float* p2 = P2 + base;
    const float* W0 = Wcheb;            // [t][o] stride 64
    const float* W1 = Wcheb + 768;
    const float* W2 = Wcheb + 1536;
    float acc = bcheb[o];
#pragma unroll
    for (int t = 0; t < T1D; ++t) {
        float w0 = W0[t * 64 + o], w1 = W1[t * 64 + o], w2 = W2[t * 64 + o];
        acc += xh[t] * (w0 - w2) - p1[t] * w1 + 2.f * p2[t] * w2;
    }
    out[g] = fmaxf(acc, 0.f);
}

extern "C" void kernel_launch(void* const* d_in, const int* in_sizes, int n_in,
                              void* d_out, int out_size, void* d_ws, size_t ws_size,
                              hipStream_t stream) {
    const float* X  = (const float*)d_in[0];
    const float* A  = (const float*)d_in[1];
    // d_in[2]=Vs, d_in[3]=bs, d_in[4]=W1, d_in[5]=W2, d_in[6]=W3 : dead code
    const float* Ve = (const float*)d_in[7];
    const float* be = (const float*)d_in[8];
    const float* U1 = (const float*)d_in[9];
    const float* U2 = (const float*)d_in[10];
    const float* U3 = (const float*)d_in[11];
    const float* Wc = (const float*)d_in[12];
    const float* bc = (const float*)d_in[13];
    float* out = (float*)d_out;

    float* w   = (float*)d_ws;
    float* dis = w + OFF_DIS;
    float* E   = w + OFF_E;
    float* Xh  = w + OFF_XH;
    float* P1  = w + OFF_P1;
    float* P2  = w + OFF_P2;

    // zero the accumulation buffers (P1,P2 contiguous)
    hipMemsetAsync(P1, 0, (size_t)2 * NN * JJ * sizeof(float), stream);

    k_deg<<<NN / 4, 256, 0, stream>>>(A, dis);
    k_prepE<<<BB, 256, 0, stream>>>(X, U1, U2, U3, be, Ve, E);
    k_xhat<<<(NN * JJ) / 256, 256, 0, stream>>>(X, E, Xh);
    k_gemm<<<dim3(NN / 32, 4), 256, 0, stream>>>(A, dis, Xh, P1);
    k_gemm<<<dim3(NN / 32, 4), 256, 0, stream>>>(A, dis, P1, P2);
    k_out<<<(BB * NN * T2D) / 256, 256, 0, stream>>>(Xh, P1, P2, Wc, bc, out);
}

// Round 3
// 195.365 us; speedup vs baseline: 1.5949x; 1.5949x over previous
//
#include <hip/hip_runtime.h>
#include <math.h>

#define NN 2048
#define BB 16
#define T1D 12
#define T2D 64
#define JJ (BB*T1D)   // 192 packed columns (b*12+u)

typedef short short8 __attribute__((ext_vector_type(8)));
typedef float f32x4 __attribute__((ext_vector_type(4)));

// workspace layout in floats
#define OFF_DIS   0
#define OFF_E     2048
#define OFF_XH    4352
#define OFF_P1    (OFF_XH + NN*JJ)        // 397568
#define OFF_P2    (OFF_P1 + NN*JJ)        // 790784
#define OFF_XHBT  (OFF_P2 + NN*JJ)        // 1184000 (ushort buf, 196608 floats)
#define OFF_P1BT  (OFF_XHBT + NN*JJ/2)    // 1380608
#define OFF_ABT   (OFF_P1BT + NN*JJ/2)    // 1577216 (2048*2048 ushort = 2097152 floats)
#define OFF_PPART (OFF_ABT + NN*NN/2)     // 3674368

__device__ inline ushort f2bf(float f) {
    union { float f; unsigned int u; } x; x.f = f;
    unsigned int u = x.u + 0x7fffu + ((x.u >> 16) & 1u);
    return (ushort)(u >> 16);
}

// ---------------- deg -> dis = rsqrt(rowsum(A)) ----------------
__global__ __launch_bounds__(256) void k_deg(const float* __restrict__ A,
                                             float* __restrict__ dis) {
    int wid = threadIdx.x >> 6, lane = threadIdx.x & 63;
    int r = blockIdx.x * 4 + wid;
    const float4* Ar = (const float4*)(A + (size_t)r * NN);
    float s = 0.f;
#pragma unroll
    for (int i = 0; i < 8; ++i) {
        float4 v = Ar[i * 64 + lane];
        s += v.x + v.y + v.z + v.w;
    }
#pragma unroll
    for (int off = 32; off > 0; off >>= 1) s += __shfl_down(s, off);
    if (lane == 0) dis[r] = (s > 0.f) ? rsqrtf(s) : 0.f;
}

// ---------------- AbT[c][k] = bf16(A[k][c]*dis[k]*dis[c]) ----------------
// 64x64 tiles through LDS; grid (32, 32)
__global__ __launch_bounds__(256) void k_conv(const float* __restrict__ A,
                                              const float* __restrict__ dis,
                                              ushort* __restrict__ AbT) {
    __shared__ float lds[64][65];
    int t = threadIdx.x;
    int c0 = blockIdx.x * 64, k0 = blockIdx.y * 64;
#pragma unroll
    for (int i = 0; i < 4; ++i) {
        int idx = t + i * 256;           // < 1024
        int kr = idx >> 4, c4 = idx & 15;
        float4 v = *(const float4*)&A[(size_t)(k0 + kr) * NN + c0 + c4 * 4];
        float dk = dis[k0 + kr];
        lds[c4 * 4 + 0][kr] = v.x * dk;
        lds[c4 * 4 + 1][kr] = v.y * dk;
        lds[c4 * 4 + 2][kr] = v.z * dk;
        lds[c4 * 4 + 3][kr] = v.w * dk;
    }
    __syncthreads();
    int cl = t >> 2, ck = (t & 3) * 16;
    float dc = dis[c0 + cl];
    union { ushort us[8]; uint4 v; } p0, p1;
#pragma unroll
    for (int e = 0; e < 8; ++e) p0.us[e] = f2bf(lds[cl][ck + e] * dc);
#pragma unroll
    for (int e = 0; e < 8; ++e) p1.us[e] = f2bf(lds[cl][ck + 8 + e] * dc);
    *(uint4*)&AbT[(size_t)(c0 + cl) * NN + k0 + ck] = p0.v;
    *(uint4*)&AbT[(size_t)(c0 + cl) * NN + k0 + ck + 8] = p1.v;
}

// ---------------- E[b] 12x12 (one block per batch) ----------------
__global__ __launch_bounds__(256) void k_prepE(const float* __restrict__ X,
                                               const float* __restrict__ U1,
                                               const float* __restrict__ U2,
                                               const float* __restrict__ U3,
                                               const float* __restrict__ be,
                                               const float* __restrict__ Ve,
                                               float* __restrict__ E_ws) {
    int b = blockIdx.x, tid = threadIdx.x;
    __shared__ float red[24][256];
    __shared__ float es[T1D][T1D];

    float accr[T1D], accc[T1D];
#pragma unroll
    for (int t = 0; t < T1D; ++t) { accr[t] = 0.f; accc[t] = 0.f; }

    for (int n = tid; n < NN; n += 256) {
        const float* xp = X + ((size_t)b * NN + n) * T1D;
        float x[T1D];
        *(float4*)&x[0] = *(const float4*)&xp[0];
        *(float4*)&x[4] = *(const float4*)&xp[4];
        *(float4*)&x[8] = *(const float4*)&xp[8];
        float u1 = U1[n], u2 = U2[n];
#pragma unroll
        for (int t = 0; t < T1D; ++t) {
            accr[t] += x[t] * u1;
            accc[t] += x[t] * u2;
        }
    }
#pragma unroll
    for (int t = 0; t < T1D; ++t) {
        red[t][tid] = accr[t];
        red[12 + t][tid] = accc[t];
    }
    __syncthreads();
    for (int s = 128; s > 0; s >>= 1) {
        if (tid < s) {
#pragma unroll
            for (int a = 0; a < 24; ++a) red[a][tid] += red[a][tid + s];
        }
        __syncthreads();
    }

    float u3 = U3[0];
    if (tid < T1D) {
        int s = tid;
        float cs = red[12 + s][0] * u3;
        float vals[T1D];
        float m = -1e30f;
#pragma unroll
        for (int t = 0; t < T1D; ++t) {
            vals[t] = red[t][0] * cs + be[t * T1D + s];
            m = fmaxf(m, vals[t]);
        }
        float sum = 0.f;
#pragma unroll
        for (int t = 0; t < T1D; ++t) { vals[t] = expf(vals[t] - m); sum += vals[t]; }
        float inv = 1.f / sum;
#pragma unroll
        for (int t = 0; t < T1D; ++t) es[t][s] = vals[t] * inv;
    }
    __syncthreads();
    if (tid < T1D) {
        int u = tid;
        float vals[T1D];
        float m = -1e30f;
#pragma unroll
        for (int t = 0; t < T1D; ++t) {
            float acc = 0.f;
#pragma unroll
            for (int s = 0; s < T1D; ++s) acc += Ve[t * T1D + s] * es[s][u];
            vals[t] = acc;
            m = fmaxf(m, acc);
        }
        float sum = 0.f;
#pragma unroll
        for (int t = 0; t < T1D; ++t) { vals[t] = expf(vals[t] - m); sum += vals[t]; }
        float inv = 1.f / sum;
#pragma unroll
        for (int t = 0; t < T1D; ++t) E_ws[b * 144 + t * T1D + u] = vals[t] * inv;
    }
}

// ---------------- X_hat packed as Xh[n][b*12+u] ----------------
__global__ __launch_bounds__(256) void k_xhat(const float* __restrict__ X,
                                              const float* __restrict__ E_ws,
                                              float* __restrict__ Xh) {
    int g = blockIdx.x * 256 + threadIdx.x;  // < NN*JJ
    int n = g / JJ;
    int j = g - n * JJ;
    int b = j / T1D;
    int u = j - b * T1D;
    const float* xp = X + ((size_t)b * NN + n) * T1D;
    const float* ep = E_ws + b * 144 + u;
    float acc = 0.f;
#pragma unroll
    for (int t = 0; t < T1D; ++t) acc += xp[t] * ep[t * T1D];
    Xh[g] = acc;
}

// ---- reduce SP parts of [2048][192] fp32, write fp32 + bf16-transposed ----
// grid 128 blocks; block covers 16 rows x 192 cols.
// Also used as pure transpose-convert with SP=1 and out32 == parts.
__global__ __launch_bounds__(256) void k_redt(const float* __restrict__ parts,
                                              int SP,
                                              float* __restrict__ out32,
                                              ushort* __restrict__ outbt) {
    __shared__ float lds[16][193];
    int t = threadIdx.x;
    int c0 = blockIdx.x * 16;
    const float4* base = (const float4*)parts + (size_t)c0 * 48;  // 48 float4/row
#pragma unroll
    for (int i = 0; i < 3; ++i) {
        int idx = t + i * 256;  // < 768
        float4 s = base[idx];
        for (int p = 1; p < SP; ++p) {
            float4 v = base[(size_t)p * (NN * JJ / 4) + idx];
            s.x += v.x; s.y += v.y; s.z += v.z; s.w += v.w;
        }
        int row = idx / 48, c4 = idx % 48;
        *(float4*)&out32[(size_t)(c0 + row) * JJ + c4 * 4] = s;
        lds[row][c4 * 4 + 0] = s.x;
        lds[row][c4 * 4 + 1] = s.y;
        lds[row][c4 * 4 + 2] = s.z;
        lds[row][c4 * 4 + 3] = s.w;
    }
    __syncthreads();
    if (t < JJ) {
        union { ushort us[8]; uint4 v; } p0, p1;
#pragma unroll
        for (int n = 0; n < 8; ++n) p0.us[n] = f2bf(lds[n][t]);
#pragma unroll
        for (int n = 0; n < 8; ++n) p1.us[n] = f2bf(lds[8 + n][t]);
        *(uint4*)&outbt[(size_t)t * NN + c0] = p0.v;
        *(uint4*)&outbt[(size_t)t * NN + c0 + 8] = p1.v;
    }
}

// ---- reduce SP parts -> P2 fp32 (no transpose needed) ----
__global__ __launch_bounds__(256) void k_red2(const float* __restrict__ parts,
                                              int SP,
                                              float* __restrict__ out32) {
    int g = blockIdx.x * 256 + threadIdx.x;  // < NN*JJ/4
    const float4* base = (const float4*)parts;
    float4 s = base[g];
    for (int p = 1; p < SP; ++p) {
        float4 v = base[(size_t)p * (NN * JJ / 4) + g];
        s.x += v.x; s.y += v.y; s.z += v.z; s.w += v.w;
    }
    ((float4*)out32)[g] = s;
}

// ---------------- MFMA GEMM: Ppart[s][c][j] = sum_k AbT[c][k]*Zbt[j][k] ------
// grid (32 c-blocks, SP k-splits), 256 thr = 4 waves, wave owns 16 c x 192 j.
// No LDS: both fragments are contiguous 16B global loads.
__global__ __launch_bounds__(256) void k_gemm(const ushort* __restrict__ AbT,
                                              const ushort* __restrict__ Zbt,
                                              float* __restrict__ Ppart,
                                              int Ksplit, int nch) {
    int tid = threadIdx.x;
    int wave = tid >> 6, lane = tid & 63;
    int jl = lane & 15;          // fragment row/col selector
    int kl = (lane >> 4) * 8;    // fragment k-offset
    int c0 = blockIdx.x * 64 + wave * 16;
    int kbase = blockIdx.y * Ksplit + kl;

    const ushort* arow = AbT + (size_t)(c0 + jl) * NN;
    f32x4 acc[12];
#pragma unroll
    for (int n = 0; n < 12; ++n) acc[n] = (f32x4)0.f;

    for (int ch = 0; ch < nch; ++ch) {
        int koff = kbase + ch * 32;
        short8 bfr[12];
#pragma unroll
        for (int n = 0; n < 12; ++n)
            bfr[n] = *(const short8*)&Zbt[(size_t)(n * 16 + jl) * NN + koff];
        short8 a = *(const short8*)&arow[koff];
#pragma unroll
        for (int n = 0; n < 12; ++n)
            acc[n] = __builtin_amdgcn_mfma_f32_16x16x32_bf16(a, bfr[n], acc[n], 0, 0, 0);
    }

    float* Pp = Ppart + (size_t)blockIdx.y * (NN * JJ);
    int crow = c0 + (lane >> 4) * 4;   // C/D: row = 4*(lane>>4)+reg, col = lane&15
#pragma unroll
    for (int n = 0; n < 12; ++n) {
#pragma unroll
        for (int r = 0; r < 4; ++r)
            Pp[(size_t)(crow + r) * JJ + n * 16 + jl] = acc[n][r];
    }
}

// ---------------- out = relu(Xh(W0-W2) - P1*W1 + 2*P2*W2 + bcheb) ----------------
__global__ __launch_bounds__(256) void k_out(const float* __restrict__ Xh,
                                             const float* __restrict__ P1,
                                             const float* __restrict__ P2,
                                             const float* __restrict__ Wcheb,
                                             const float* __restrict__ bcheb,
                                             float* __restrict__ out) {
    int g = blockIdx.x * 256 + threadIdx.x;  // < BB*NN*T2D
    int o = g & 63;
    int row = g >> 6;          // b*2048+n
    int b = row >> 11;
    int n = row & 2047;
    int base = n * JJ + b * T1D;
    const float* xh = Xh + base;
    const float* p1 = P1 + base;
    const float* p2 = P2 + base;
    const float* W0 = Wcheb;            // [t][o] stride 64
    const float* W1 = Wcheb + 768;
    const float* W2 = Wcheb + 1536;
    float acc = bcheb[o];
#pragma unroll
    for (int t = 0; t < T1D; ++t) {
        float w0 = W0[t * 64 + o], w1 = W1[t * 64 + o], w2 = W2[t * 64 + o];
        acc += xh[t] * (w0 - w2) - p1[t] * w1 + 2.f * p2[t] * w2;
    }
    out[g] = fmaxf(acc, 0.f);
}

extern "C" void kernel_launch(void* const* d_in, const int* in_sizes, int n_in,
                              void* d_out, int out_size, void* d_ws, size_t ws_size,
                              hipStream_t stream) {
    const float* X  = (const float*)d_in[0];
    const float* A  = (const float*)d_in[1];
    // d_in[2]=Vs, d_in[3]=bs, d_in[4]=W1, d_in[5]=W2, d_in[6]=W3 : dead code
    const float* Ve = (const float*)d_in[7];
    const float* be = (const float*)d_in[8];
    const float* U1 = (const float*)d_in[9];
    const float* U2 = (const float*)d_in[10];
    const float* U3 = (const float*)d_in[11];
    const float* Wc = (const float*)d_in[12];
    const float* bc = (const float*)d_in[13];
    float* out = (float*)d_out;

    float* w     = (float*)d_ws;
    float* dis   = w + OFF_DIS;
    float* E     = w + OFF_E;
    float* Xh    = w + OFF_XH;
    float* P1    = w + OFF_P1;
    float* P2    = w + OFF_P2;
    ushort* Xhbt = (ushort*)(w + OFF_XHBT);
    ushort* P1bt = (ushort*)(w + OFF_P1BT);
    ushort* AbT  = (ushort*)(w + OFF_ABT);
    float* Ppart = w + OFF_PPART;

    // choose split-K so workspace fits (identical every call: ws_size is fixed)
    int SP = 8;
    while (SP > 1 && ((size_t)OFF_PPART + (size_t)SP * NN * JJ) * 4 > ws_size) SP >>= 1;
    int Ksplit = NN / SP;
    int nch = Ksplit / 32;

    k_deg<<<NN / 4, 256, 0, stream>>>(A, dis);
    k_conv<<<dim3(32, 32), 256, 0, stream>>>(A, dis, AbT);
    k_prepE<<<BB, 256, 0, stream>>>(X, U1, U2, U3, be, Ve, E);
    k_xhat<<<(NN * JJ) / 256, 256, 0, stream>>>(X, E, Xh);
    // transpose-convert Xh -> Xhbt (SP=1: also rewrites Xh with itself, harmless)
    k_redt<<<NN / 16, 256, 0, stream>>>(Xh, 1, Xh, Xhbt);
    k_gemm<<<dim3(NN / 64, SP), 256, 0, stream>>>(AbT, Xhbt, Ppart, Ksplit, nch);
    k_redt<<<NN / 16, 256, 0, stream>>>(Ppart, SP, P1, P1bt);
    k_gemm<<<dim3(NN / 64, SP), 256, 0, stream>>>(AbT, P1bt, Ppart, Ksplit, nch);
    k_red2<<<(NN * JJ / 4) / 256, 256, 0, stream>>>(Ppart, SP, P2);
    k_out<<<(BB * NN * T2D) / 256, 256, 0, stream>>>(Xh, P1, P2, Wc, bc, out);
}

// Round 4
// 180.583 us; speedup vs baseline: 1.7254x; 1.0819x over previous
//
#include <hip/hip_runtime.h>
#include <math.h>

#define NN 2048
#define BB 16
#define T1D 12
#define T2D 64
#define JJ 192   // packed columns (b*12+u)

typedef short short8 __attribute__((ext_vector_type(8)));
typedef float f32x4 __attribute__((ext_vector_type(4)));

// workspace layout in floats (~14.7 MB total)
#define OFF_DIS   0
#define OFF_E     2048                    // 2304 floats (16 x 144)
#define OFF_XH    4608
#define OFF_P1    (OFF_XH + NN*JJ)
#define OFF_P2    (OFF_P1 + NN*JJ)
#define OFF_XHBT  (OFF_P2 + NN*JJ)        // ushort buf, NN*JJ/2 floats
#define OFF_P1BT  (OFF_XHBT + NN*JJ/2)
#define OFF_ABT   (OFF_P1BT + NN*JJ/2)    // 2048*2048 ushort

__device__ inline ushort f2bf(float f) {
    union { float f; unsigned int u; } x; x.f = f;
    unsigned int u = x.u + 0x7fffu + ((x.u >> 16) & 1u);
    return (ushort)(u >> 16);
}

// ============ dispatch 1: deg rowsums (blocks 0..511) + E prep (512..527) ====
__global__ __launch_bounds__(256) void k_degE(const float* __restrict__ A,
                                              const float* __restrict__ X,
                                              const float* __restrict__ U1,
                                              const float* __restrict__ U2,
                                              const float* __restrict__ U3,
                                              const float* __restrict__ be,
                                              const float* __restrict__ Ve,
                                              float* __restrict__ dis,
                                              float* __restrict__ E_ws) {
    __shared__ float red[24][256];
    __shared__ float es[T1D][T1D];
    int tid = threadIdx.x;

    if (blockIdx.x < 512) {
        // ---- deg -> dis = rsqrt(rowsum(A)), one wave per row ----
        int wid = tid >> 6, lane = tid & 63;
        int r = blockIdx.x * 4 + wid;
        const float4* Ar = (const float4*)(A + (size_t)r * NN);
        float s = 0.f;
#pragma unroll
        for (int i = 0; i < 8; ++i) {
            float4 v = Ar[i * 64 + lane];
            s += v.x + v.y + v.z + v.w;
        }
#pragma unroll
        for (int off = 32; off > 0; off >>= 1) s += __shfl_down(s, off);
        if (lane == 0) dis[r] = (s > 0.f) ? rsqrtf(s) : 0.f;
        return;
    }

    // ---- E[b] 12x12 ----
    int b = blockIdx.x - 512;
    float accr[T1D], accc[T1D];
#pragma unroll
    for (int t = 0; t < T1D; ++t) { accr[t] = 0.f; accc[t] = 0.f; }
    for (int n = tid; n < NN; n += 256) {
        const float* xp = X + ((size_t)b * NN + n) * T1D;
        float x[T1D];
        *(float4*)&x[0] = *(const float4*)&xp[0];
        *(float4*)&x[4] = *(const float4*)&xp[4];
        *(float4*)&x[8] = *(const float4*)&xp[8];
        float u1 = U1[n], u2 = U2[n];
#pragma unroll
        for (int t = 0; t < T1D; ++t) {
            accr[t] += x[t] * u1;
            accc[t] += x[t] * u2;
        }
    }
#pragma unroll
    for (int t = 0; t < T1D; ++t) {
        red[t][tid] = accr[t];
        red[12 + t][tid] = accc[t];
    }
    __syncthreads();
    for (int s = 128; s > 0; s >>= 1) {
        if (tid < s) {
#pragma unroll
            for (int a = 0; a < 24; ++a) red[a][tid] += red[a][tid + s];
        }
        __syncthreads();
    }
    float u3 = U3[0];
    if (tid < T1D) {          // softmax over t per column s
        int s = tid;
        float cs = red[12 + s][0] * u3;
        float vals[T1D];
        float m = -1e30f;
#pragma unroll
        for (int t = 0; t < T1D; ++t) {
            vals[t] = red[t][0] * cs + be[t * T1D + s];
            m = fmaxf(m, vals[t]);
        }
        float sum = 0.f;
#pragma unroll
        for (int t = 0; t < T1D; ++t) { vals[t] = expf(vals[t] - m); sum += vals[t]; }
        float inv = 1.f / sum;
#pragma unroll
        for (int t = 0; t < T1D; ++t) es[t][s] = vals[t] * inv;
    }
    __syncthreads();
    if (tid < T1D) {          // Ve @ es, softmax over t, store E
        int u = tid;
        float vals[T1D];
        float m = -1e30f;
#pragma unroll
        for (int t = 0; t < T1D; ++t) {
            float acc = 0.f;
#pragma unroll
            for (int s = 0; s < T1D; ++s) acc += Ve[t * T1D + s] * es[s][u];
            vals[t] = acc;
            m = fmaxf(m, acc);
        }
        float sum = 0.f;
#pragma unroll
        for (int t = 0; t < T1D; ++t) { vals[t] = expf(vals[t] - m); sum += vals[t]; }
        float inv = 1.f / sum;
#pragma unroll
        for (int t = 0; t < T1D; ++t) E_ws[b * 144 + t * T1D + u] = vals[t] * inv;
    }
}

// ==== dispatch 2: AbT convert (blocks 0..1023) + Xh/Xhbt (1024..1151) ========
__global__ __launch_bounds__(256) void k_mid(const float* __restrict__ A,
                                             const float* __restrict__ dis,
                                             const float* __restrict__ X,
                                             const float* __restrict__ E_ws,
                                             ushort* __restrict__ AbT,
                                             float* __restrict__ Xh,
                                             ushort* __restrict__ Xhbt) {
    __shared__ float lds[5504];
    int t = threadIdx.x;

    if (blockIdx.x < 1024) {
        // ---- AbT[c][k] = bf16(A[k][c]*dis[k]*dis[c]), 64x64 tile ----
        int c0 = (blockIdx.x & 31) * 64, k0 = (blockIdx.x >> 5) * 64;
#pragma unroll
        for (int i = 0; i < 4; ++i) {
            int idx = t + i * 256;           // < 1024
            int kr = idx >> 4, c4 = idx & 15;
            float4 v = *(const float4*)&A[(size_t)(k0 + kr) * NN + c0 + c4 * 4];
            float dk = dis[k0 + kr];
            lds[(c4 * 4 + 0) * 65 + kr] = v.x * dk;
            lds[(c4 * 4 + 1) * 65 + kr] = v.y * dk;
            lds[(c4 * 4 + 2) * 65 + kr] = v.z * dk;
            lds[(c4 * 4 + 3) * 65 + kr] = v.w * dk;
        }
        __syncthreads();
        int cl = t >> 2, ck = (t & 3) * 16;
        float dc = dis[c0 + cl];
        union { ushort us[8]; uint4 v; } p0, p1;
#pragma unroll
        for (int e = 0; e < 8; ++e) p0.us[e] = f2bf(lds[cl * 65 + ck + e] * dc);
#pragma unroll
        for (int e = 0; e < 8; ++e) p1.us[e] = f2bf(lds[cl * 65 + ck + 8 + e] * dc);
        *(uint4*)&AbT[(size_t)(c0 + cl) * NN + k0 + ck] = p0.v;
        *(uint4*)&AbT[(size_t)(c0 + cl) * NN + k0 + ck + 8] = p1.v;
        return;
    }

    // ---- Xh[n][b*12+u] + bf16 transpose Xhbt[j][n], 16 n-rows per block ----
    int n0 = (blockIdx.x - 1024) * 16;
    float* EL = lds + 3200;                 // E copy: 2304 floats
#pragma unroll
    for (int i = 0; i < 9; ++i) {
        int idx = t + i * 256;
        if (idx < 2304) EL[idx] = E_ws[idx];
    }
    __syncthreads();
    {
        int nr = t >> 4, b = t & 15;
        const float* xp = X + ((size_t)b * NN + n0 + nr) * T1D;
        float x[T1D];
        *(float4*)&x[0] = *(const float4*)&xp[0];
        *(float4*)&x[4] = *(const float4*)&xp[4];
        *(float4*)&x[8] = *(const float4*)&xp[8];
        const float* Eb = EL + b * 144;
#pragma unroll
        for (int u = 0; u < T1D; ++u) {
            float acc = 0.f;
#pragma unroll
            for (int tt = 0; tt < T1D; ++tt) acc += x[tt] * Eb[tt * T1D + u];
            lds[nr * 200 + b * T1D + u] = acc;
        }
    }
    __syncthreads();
#pragma unroll
    for (int i = 0; i < 3; ++i) {
        int idx4 = t + i * 256;             // < 768
        int row = idx4 / 48, c4 = idx4 % 48;
        *(float4*)&Xh[(size_t)(n0 + row) * JJ + c4 * 4] =
            *(float4*)&lds[row * 200 + c4 * 4];
    }
    if (t < JJ) {
        union { ushort us[8]; uint4 v; } p0, p1;
#pragma unroll
        for (int nr = 0; nr < 8; ++nr) p0.us[nr] = f2bf(lds[nr * 200 + t]);
#pragma unroll
        for (int nr = 0; nr < 8; ++nr) p1.us[nr] = f2bf(lds[(8 + nr) * 200 + t]);
        *(uint4*)&Xhbt[(size_t)t * NN + n0] = p0.v;
        *(uint4*)&Xhbt[(size_t)t * NN + n0 + 8] = p1.v;
    }
}

// ==== GEMM: P[c][j] = sum_k AbT[c][k]*Zbt[j][k], split-K inside block ========
// grid (128 c-tiles, 4 j-slices) x 512 thr (8 waves); wave w owns K [w*256,+256)
template<int NFRAG, bool WBT>
__global__ __launch_bounds__(512) void k_gemm(const ushort* __restrict__ AbT,
                                              const ushort* __restrict__ Zbt,
                                              float* __restrict__ P,
                                              ushort* __restrict__ Pbt) {
    __shared__ float lds[8 * NFRAG * 64 * 4];
    int tid = threadIdx.x;
    int wave = tid >> 6, lane = tid & 63;
    int jl = lane & 15;
    int kl = (lane >> 4) * 8;
    int c0 = blockIdx.x * 16;
    int j0 = blockIdx.y * (16 * NFRAG);
    int kbase = wave * 256 + kl;

    const ushort* arow = AbT + (size_t)(c0 + jl) * NN + kbase;
    f32x4 acc[NFRAG];
#pragma unroll
    for (int n = 0; n < NFRAG; ++n) acc[n] = (f32x4)0.f;

#pragma unroll
    for (int ch = 0; ch < 8; ++ch) {
        int koff = ch * 32;
        short8 a = *(const short8*)&arow[koff];
        short8 bfr[NFRAG];
#pragma unroll
        for (int n = 0; n < NFRAG; ++n)
            bfr[n] = *(const short8*)&Zbt[(size_t)(j0 + n * 16 + jl) * NN + kbase + koff];
#pragma unroll
        for (int n = 0; n < NFRAG; ++n)
            acc[n] = __builtin_amdgcn_mfma_f32_16x16x32_bf16(a, bfr[n], acc[n], 0, 0, 0);
    }

#pragma unroll
    for (int n = 0; n < NFRAG; ++n)
        *(f32x4*)&lds[((wave * NFRAG + n) * 64 + lane) * 4] = acc[n];
    __syncthreads();

    const int NOUT = 16 * 16 * NFRAG;
    for (int o = tid; o < NOUT; o += 512) {
        int c_idx = o / (16 * NFRAG);
        int j_idx = o % (16 * NFRAG);
        int n = j_idx >> 4, col = j_idx & 15;
        int lidx = ((c_idx >> 2) * 16 + col) * 4 + (c_idx & 3);
        float s = 0.f;
#pragma unroll
        for (int w = 0; w < 8; ++w) s += lds[(w * NFRAG + n) * 256 + lidx];
        P[(size_t)(c0 + c_idx) * JJ + j0 + j_idx] = s;
        if (WBT) Pbt[(size_t)(j0 + j_idx) * NN + c0 + c_idx] = f2bf(s);
    }
}

// ==== out = relu(Xh(W0-W2) - P1*W1 + 2*P2*W2 + bcheb) ========================
__global__ __launch_bounds__(256) void k_out(const float* __restrict__ Xh,
                                             const float* __restrict__ P1,
                                             const float* __restrict__ P2,
                                             const float* __restrict__ Wcheb,
                                             const float* __restrict__ bcheb,
                                             float* __restrict__ out) {
    int g = blockIdx.x * 256 + threadIdx.x;  // < BB*NN*T2D
    int o = g & 63;
    int row = g >> 6;          // b*2048+n
    int b = row >> 11;
    int n = row & 2047;
    int base = n * JJ + b * T1D;
    const float* xh = Xh + base;
    const float* p1 = P1 + base;
    const float* p2 = P2 + base;
    const float* W0 = Wcheb;            // [t][o] stride 64
    const float* W1 = Wcheb + 768;
    const float* W2 = Wcheb + 1536;
    float acc = bcheb[o];
#pragma unroll
    for (int t = 0; t < T1D; ++t) {
        float w0 = W0[t * 64 + o], w1 = W1[t * 64 + o], w2 = W2[t * 64 + o];
        acc += xh[t] * (w0 - w2) - p1[t] * w1 + 2.f * p2[t] * w2;
    }
    out[g] = fmaxf(acc, 0.f);
}

extern "C" void kernel_launch(void* const* d_in, const int* in_sizes, int n_in,
                              void* d_out, int out_size, void* d_ws, size_t ws_size,
                              hipStream_t stream) {
    const float* X  = (const float*)d_in[0];
    const float* A  = (const float*)d_in[1];
    // d_in[2]=Vs, d_in[3]=bs, d_in[4]=W1, d_in[5]=W2, d_in[6]=W3 : dead code
    const float* Ve = (const float*)d_in[7];
    const float* be = (const float*)d_in[8];
    const float* U1 = (const float*)d_in[9];
    const float* U2 = (const float*)d_in[10];
    const float* U3 = (const float*)d_in[11];
    const float* Wc = (const float*)d_in[12];
    const float* bc = (const float*)d_in[13];
    float* out = (float*)d_out;

    float* w     = (float*)d_ws;
    float* dis   = w + OFF_DIS;
    float* E     = w + OFF_E;
    float* Xh    = w + OFF_XH;
    float* P1    = w + OFF_P1;
    float* P2    = w + OFF_P2;
    ushort* Xhbt = (ushort*)(w + OFF_XHBT);
    ushort* P1bt = (ushort*)(w + OFF_P1BT);
    ushort* AbT  = (ushort*)(w + OFF_ABT);

    k_degE<<<528, 256, 0, stream>>>(A, X, U1, U2, U3, be, Ve, dis, E);
    k_mid<<<1152, 256, 0, stream>>>(A, dis, X, E, AbT, Xh, Xhbt);
    k_gemm<3, true ><<<dim3(128, 4), 512, 0, stream>>>(AbT, Xhbt, P1, P1bt);
    k_gemm<3, false><<<dim3(128, 4), 512, 0, stream>>>(AbT, P1bt, P2, nullptr);
    k_out<<<(BB * NN * T2D) / 256, 256, 0, stream>>>(Xh, P1, P2, Wc, bc, out);
}